// Round 3
// baseline (397.466 us; speedup 1.0000x reference)
//
#include <hip/hip_runtime.h>

#define B_ 4
#define C_ 256
#define CI_ 128
#define N_ 4096
#define OC_ 256

typedef __bf16 bf16x8 __attribute__((ext_vector_type(8)));
typedef float f32x4 __attribute__((ext_vector_type(4)));

#define MFMA16(a, b, c) __builtin_amdgcn_mfma_f32_16x16x32_bf16((a), (b), (c), 0, 0, 0)

__device__ __forceinline__ unsigned f2bf(float f) {
  unsigned u = __float_as_uint(f);
  return (u + 0x7fffu + ((u >> 16) & 1u)) >> 16;
}
__device__ __forceinline__ float b2f(unsigned h) { return __uint_as_float(h << 16); }
__device__ __forceinline__ bf16x8 ld8(const unsigned short* p) {
  return *reinterpret_cast<const bf16x8*>(p);
}

// ---------- transpose+convert: x f32 [B][256][4096] -> Xt bf16 [B][4096][256] ----------
__global__ __launch_bounds__(256) void dpf_tkern(const float* __restrict__ x1,
                                                 const float* __restrict__ x2,
                                                 unsigned short* __restrict__ xt) {
  __shared__ float lt[64][65];
  int bid = blockIdx.x;
  int src = bid >> 10, rem = bid & 1023;
  int b = rem >> 8, ct = (rem >> 6) & 3, nt = rem & 63;
  const float* x = src ? x2 : x1;
  unsigned short* dst = xt + (size_t)src * ((size_t)B_ * N_ * C_);
  int t = threadIdx.x;
  int cl = t >> 2, nlo = (t & 3) << 4;
  const float* rp = x + ((size_t)(b * C_ + ct * 64 + cl)) * N_ + nt * 64 + nlo;
#pragma unroll
  for (int q = 0; q < 4; ++q) {
    float4 v = *reinterpret_cast<const float4*>(rp + q * 4);
    lt[cl][nlo + q * 4 + 0] = v.x;
    lt[cl][nlo + q * 4 + 1] = v.y;
    lt[cl][nlo + q * 4 + 2] = v.z;
    lt[cl][nlo + q * 4 + 3] = v.w;
  }
  __syncthreads();
  int nl = t & 63, cb = (t >> 6) << 4;
  unsigned h[16];
#pragma unroll
  for (int q = 0; q < 16; ++q) h[q] = f2bf(lt[cb + q][nl]);
  uint4 u0, u1;
  u0.x = h[0] | (h[1] << 16); u0.y = h[2] | (h[3] << 16);
  u0.z = h[4] | (h[5] << 16); u0.w = h[6] | (h[7] << 16);
  u1.x = h[8] | (h[9] << 16); u1.y = h[10] | (h[11] << 16);
  u1.z = h[12] | (h[13] << 16); u1.w = h[14] | (h[15] << 16);
  unsigned short* op = dst + ((size_t)(b * N_ + nt * 64 + nl)) * C_ + ct * 64 + cb;
  *reinterpret_cast<uint4*>(op) = u0;
  *reinterpret_cast<uint4*>(op + 8) = u1;
}

// ---------- weight convert to bf16 ----------
__global__ __launch_bounds__(256) void dpf_wckern(
    const float* __restrict__ Wq, const float* __restrict__ Wk, const float* __restrict__ Wv,
    const float* __restrict__ Wp, unsigned short* __restrict__ Wqb, unsigned short* __restrict__ Wkb,
    unsigned short* __restrict__ Wvb, unsigned short* __restrict__ Wpb) {
  int bid = blockIdx.x;
  const float* src;
  unsigned short* dst;
  int lb;
  if (bid < 16) { src = Wq; dst = Wqb; lb = bid; }
  else if (bid < 32) { src = Wk; dst = Wkb; lb = bid - 16; }
  else if (bid < 48) { src = Wv; dst = Wvb; lb = bid - 32; }
  else { src = Wp; dst = Wpb; lb = bid - 48; }
  int o = lb * 2048 + threadIdx.x * 8;
  float4 a = *reinterpret_cast<const float4*>(src + o);
  float4 c = *reinterpret_cast<const float4*>(src + o + 4);
  uint4 u;
  u.x = f2bf(a.x) | (f2bf(a.y) << 16);
  u.y = f2bf(a.z) | (f2bf(a.w) << 16);
  u.z = f2bf(c.x) | (f2bf(c.y) << 16);
  u.w = f2bf(c.z) | (f2bf(c.w) << 16);
  *reinterpret_cast<uint4*>(dst + o) = u;
}

// ---------- projections: Q,K -> [b][n][c]; V1,V2 -> [b][c][n] ----------
__global__ __launch_bounds__(256, 2) void dpf_pkern(
    const unsigned short* __restrict__ Xt, const unsigned short* __restrict__ Wqb,
    const unsigned short* __restrict__ Wkb, const unsigned short* __restrict__ Wvb,
    const float* __restrict__ bq, const float* __restrict__ sq, const float* __restrict__ tq,
    const float* __restrict__ bk, const float* __restrict__ sk, const float* __restrict__ tk,
    const float* __restrict__ bv, const float* __restrict__ sv, const float* __restrict__ tv,
    unsigned short* __restrict__ Qg, unsigned short* __restrict__ Kg,
    unsigned short* __restrict__ V1g, unsigned short* __restrict__ V2g) {
  int bid = blockIdx.x;
  int g = bid >> 7, b = (bid >> 5) & 3, nt = bid & 31;
  int n0 = nt * 128;
  int t = threadIdx.x, lane = t & 63, wid = t >> 6;
  int wo = wid >> 1, wn = wid & 1;
  int lrow = lane & 15, lhi = lane >> 4;

  const unsigned short* W = (g == 0) ? Wqb : (g == 1) ? Wkb : Wvb;
  const unsigned short* X = Xt + ((g == 0 || g == 2) ? (size_t)0 : (size_t)B_ * N_ * C_);
  const float* bb = (g == 0) ? bq : (g == 1) ? bk : bv;
  const float* ss = (g == 0) ? sq : (g == 1) ? sk : sv;
  const float* tt = (g == 0) ? tq : (g == 1) ? tk : tv;
  const float extra = (g < 2) ? 0.29730177875068026f : 1.0f;  // 128^-0.25 folded into Q and K

  f32x4 acc[4][4];
#pragma unroll
  for (int i = 0; i < 4; ++i)
#pragma unroll
    for (int jj = 0; jj < 4; ++jj) acc[i][jj] = (f32x4){0.f, 0.f, 0.f, 0.f};

  const unsigned short* wbase = W + (size_t)(64 * wo + lrow) * C_ + 8 * lhi;
  const unsigned short* xbase = X + ((size_t)(b * N_ + n0 + 64 * wn + lrow)) * C_ + 8 * lhi;

  for (int ks = 0; ks < 8; ++ks) {
    bf16x8 wf[4], xf[4];
#pragma unroll
    for (int of = 0; of < 4; ++of) wf[of] = ld8(wbase + (size_t)(16 * of) * C_ + 32 * ks);
#pragma unroll
    for (int nf = 0; nf < 4; ++nf) xf[nf] = ld8(xbase + (size_t)(16 * nf) * C_ + 32 * ks);
    if (g < 2) {
#pragma unroll
      for (int of = 0; of < 4; ++of)
#pragma unroll
        for (int nf = 0; nf < 4; ++nf) acc[of][nf] = MFMA16(wf[of], xf[nf], acc[of][nf]);
    } else {
#pragma unroll
      for (int of = 0; of < 4; ++of)
#pragma unroll
        for (int nf = 0; nf < 4; ++nf) acc[of][nf] = MFMA16(xf[nf], wf[of], acc[of][nf]);
    }
  }

  if (g < 2) {
    // D: row = o (4*lhi+r), col = n (lrow); store [n][c] packed over o
    unsigned short* dst = (g == 0) ? Qg : Kg;
#pragma unroll
    for (int of = 0; of < 4; ++of) {
      int ob = 64 * wo + 16 * of + 4 * lhi;
      float4 s4 = *reinterpret_cast<const float4*>(ss + ob);
      float4 b4 = *reinterpret_cast<const float4*>(bb + ob);
      float4 t4 = *reinterpret_cast<const float4*>(tt + ob);
      float sc0 = s4.x * extra, sc1 = s4.y * extra, sc2 = s4.z * extra, sc3 = s4.w * extra;
      float sh0 = (b4.x * s4.x + t4.x) * extra, sh1 = (b4.y * s4.y + t4.y) * extra;
      float sh2 = (b4.z * s4.z + t4.z) * extra, sh3 = (b4.w * s4.w + t4.w) * extra;
#pragma unroll
      for (int nf = 0; nf < 4; ++nf) {
        int n = n0 + 64 * wn + 16 * nf + lrow;
        float y0 = fmaxf(acc[of][nf][0] * sc0 + sh0, 0.f);
        float y1 = fmaxf(acc[of][nf][1] * sc1 + sh1, 0.f);
        float y2 = fmaxf(acc[of][nf][2] * sc2 + sh2, 0.f);
        float y3 = fmaxf(acc[of][nf][3] * sc3 + sh3, 0.f);
        uint2 pk;
        pk.x = f2bf(y0) | (f2bf(y1) << 16);
        pk.y = f2bf(y2) | (f2bf(y3) << 16);
        *reinterpret_cast<uint2*>(dst + ((size_t)(b * N_ + n)) * CI_ + ob) = pk;
      }
    }
  } else {
    // D: row = n (4*lhi+r), col = o (lrow); store [c][n] packed over n
    unsigned short* dst = (g == 2) ? V1g : V2g;
#pragma unroll
    for (int of = 0; of < 4; ++of) {
      int o = 64 * wo + 16 * of + lrow;
      float sc = ss[o];
      float sh = bb[o] * sc + tt[o];
#pragma unroll
      for (int nf = 0; nf < 4; ++nf) {
        int nb = n0 + 64 * wn + 16 * nf + 4 * lhi;
        float y0 = fmaxf(acc[of][nf][0] * sc + sh, 0.f);
        float y1 = fmaxf(acc[of][nf][1] * sc + sh, 0.f);
        float y2 = fmaxf(acc[of][nf][2] * sc + sh, 0.f);
        float y3 = fmaxf(acc[of][nf][3] * sc + sh, 0.f);
        uint2 pk;
        pk.x = f2bf(y0) | (f2bf(y1) << 16);
        pk.y = f2bf(y2) | (f2bf(y3) << 16);
        *reinterpret_cast<uint2*>(dst + ((size_t)(b * CI_ + o)) * N_ + nb) = pk;
      }
    }
  }
}

// ---------- column sums of V over n: colsum[0]=sum V2, colsum[1]=sum V1 ----------
__global__ __launch_bounds__(256) void dpf_cskern(const unsigned short* __restrict__ V1g,
                                                  const unsigned short* __restrict__ V2g,
                                                  float* __restrict__ colsum) {
  __shared__ float ps[4];
  int bid = blockIdx.x;
  int vs = bid >> 9, b = (bid >> 7) & 3, c = bid & 127;
  const unsigned short* src = (vs == 0 ? V2g : V1g) + ((size_t)(b * CI_ + c)) * N_;
  int t = threadIdx.x;
  float s = 0.f;
#pragma unroll
  for (int i = 0; i < 2; ++i) {
    uint4 u = *reinterpret_cast<const uint4*>(src + i * 2048 + t * 8);
    s += b2f(u.x & 0xffffu) + b2f(u.x >> 16) + b2f(u.y & 0xffffu) + b2f(u.y >> 16);
    s += b2f(u.z & 0xffffu) + b2f(u.z >> 16) + b2f(u.w & 0xffffu) + b2f(u.w >> 16);
  }
#pragma unroll
  for (int off = 1; off < 64; off <<= 1) s += __shfl_xor(s, off, 64);
  if ((t & 63) == 0) ps[t >> 6] = s;
  __syncthreads();
  if (t == 0) colsum[vs * 512 + b * 128 + c] = ps[0] + ps[1] + ps[2] + ps[3];
}

// ---------- fused complement flash-attention ----------
// grid 256, 512 threads = 8 waves = 4 m-groups x 2 waves x 32 q-rows, m-tile 32
// amdgpu_waves_per_eu(2,2): register-allocate for exactly 2 waves/SIMD (256 VGPR).
// launch_bounds' 2nd arg empirically did NOT move allocation off 128 (r1/r2:
// VGPR=128 + 791MB scratch write-back -> 260us). LDS 137KB pins 1 block/CU anyway.
__global__ __launch_bounds__(512)
__attribute__((amdgpu_waves_per_eu(2, 2))) void dpf_akern(
    const unsigned short* __restrict__ Qg, const unsigned short* __restrict__ Kg,
    const unsigned short* __restrict__ V1g, const unsigned short* __restrict__ V2g,
    const float* __restrict__ colsum, unsigned short* __restrict__ Cat) {
  extern __shared__ char smem[];
  unsigned short(*lK)[32][136] = reinterpret_cast<unsigned short(*)[32][136]>(smem);            // 34816 B
  unsigned short(*lV)[2][128][40] = reinterpret_cast<unsigned short(*)[2][128][40]>(smem + 34816);  // 81920 B
  unsigned short(*lP)[32][40] = reinterpret_cast<unsigned short(*)[32][40]>(smem + 116736);     // 20480 B
  float* mb = reinterpret_cast<float*>(smem);  // merge overlay (after main loop)

  const float L2E = 1.44269504088896f;
  int t = threadIdx.x, lane = t & 63, wid = t >> 6;
  int g = wid >> 1, j = wid & 1;
  int lrow = lane & 15, lhi = lane >> 4;

  int bid = blockIdx.x;
  int xcd = bid & 7;
  int b = xcd >> 1;                            // each XCD pair owns one batch (L2 locality)
  int qt = ((bid >> 3) << 1) | (xcd & 1);
  int n0 = qt * 64;

  // Q fragments (B-operand of S^T): lane owns one q-row per nf
  bf16x8 qf[2][4];
#pragma unroll
  for (int nf = 0; nf < 2; ++nf) {
    const unsigned short* qp = Qg + ((size_t)(b * N_ + n0 + 32 * j + 16 * nf + lrow)) * CI_ + 8 * lhi;
#pragma unroll
    for (int ks = 0; ks < 4; ++ks) qf[nf][ks] = ld8(qp + 32 * ks);
  }

  f32x4 acc[2][2][8];  // [nf][vs][cf]; O^T frags
#pragma unroll
  for (int nf = 0; nf < 2; ++nf)
#pragma unroll
    for (int vs = 0; vs < 2; ++vs)
#pragma unroll
      for (int cf = 0; cf < 8; ++cf) acc[nf][vs][cf] = (f32x4){0.f, 0.f, 0.f, 0.f};
  float mrun[2] = {-1e30f, -1e30f}, lrun[2] = {0.f, 0.f};

  int kr = t >> 4, kc = t & 15;  // K staging: row 0..31, 16B-chunk 0..15
  int vr = t >> 2, vc = t & 3;   // V staging: row 0..127, chunk 0..3
  uint4 stK[4], stV[8];

  auto issue = [&](int step) {
    int m0 = step * 128;
#pragma unroll
    for (int e = 0; e < 4; ++e)
      stK[e] = *reinterpret_cast<const uint4*>(Kg + ((size_t)(b * N_ + m0 + e * 32 + kr)) * CI_ + kc * 8);
#pragma unroll
    for (int e = 0; e < 8; ++e) {
      const unsigned short* vsrc = (e & 1) ? V1g : V2g;  // vs0 = V2 (out1), vs1 = V1 (out2)
      stV[e] = *reinterpret_cast<const uint4*>(vsrc + ((size_t)(b * CI_ + vr)) * N_ + m0 + (e >> 1) * 32 + vc * 8);
    }
  };

  issue(0);
#pragma unroll 1
  for (int step = 0; step < 32; ++step) {
#pragma unroll
    for (int e = 0; e < 4; ++e) *reinterpret_cast<uint4*>(&lK[e][kr][kc * 8]) = stK[e];
#pragma unroll
    for (int e = 0; e < 8; ++e) *reinterpret_cast<uint4*>(&lV[e >> 1][e & 1][vr][vc * 8]) = stV[e];
    __syncthreads();
    if (step < 31) issue(step + 1);  // prefetch hidden under compute

    // S^T = K . Q^T  (32m x 16n per nf)
    f32x4 sacc[2][2];
#pragma unroll
    for (int nf = 0; nf < 2; ++nf)
#pragma unroll
      for (int mf = 0; mf < 2; ++mf) sacc[nf][mf] = (f32x4){0.f, 0.f, 0.f, 0.f};
    __builtin_amdgcn_s_setprio(1);
#pragma unroll
    for (int ks = 0; ks < 4; ++ks) {
      bf16x8 kf0 = ld8(&lK[g][lrow][32 * ks + 8 * lhi]);
      bf16x8 kf1 = ld8(&lK[g][16 + lrow][32 * ks + 8 * lhi]);
#pragma unroll
      for (int nf = 0; nf < 2; ++nf) {
        sacc[nf][0] = MFMA16(kf0, qf[nf][ks], sacc[nf][0]);
        sacc[nf][1] = MFMA16(kf1, qf[nf][ks], sacc[nf][1]);
      }
    }
    __builtin_amdgcn_s_setprio(0);

    // online softmax per q-row (one row per lane per nf), P -> LDS
#pragma unroll
    for (int nf = 0; nf < 2; ++nf) {
      float smax = fmaxf(fmaxf(fmaxf(sacc[nf][0][0], sacc[nf][0][1]), fmaxf(sacc[nf][0][2], sacc[nf][0][3])),
                         fmaxf(fmaxf(sacc[nf][1][0], sacc[nf][1][1]), fmaxf(sacc[nf][1][2], sacc[nf][1][3])));
      smax = fmaxf(smax, __shfl_xor(smax, 16, 64));
      smax = fmaxf(smax, __shfl_xor(smax, 32, 64));
      // T13 defer-rescale: skip the acc pass while max growth <= 8 (wave-uniform)
      if (!__all(smax - mrun[nf] <= 8.0f)) {
        float mnew = fmaxf(mrun[nf], smax);
        float fsc = __builtin_amdgcn_exp2f((mrun[nf] - mnew) * L2E);
        mrun[nf] = mnew;
        lrun[nf] *= fsc;
#pragma unroll
        for (int vs = 0; vs < 2; ++vs)
#pragma unroll
          for (int cf = 0; cf < 8; ++cf) acc[nf][vs][cf] *= fsc;
      }
      float p[2][4];
      float ls = 0.f;
#pragma unroll
      for (int mf = 0; mf < 2; ++mf)
#pragma unroll
        for (int r = 0; r < 4; ++r) {
          p[mf][r] = __builtin_amdgcn_exp2f((sacc[nf][mf][r] - mrun[nf]) * L2E);
          ls += p[mf][r];
        }
      ls += __shfl_xor(ls, 16, 64);
      ls += __shfl_xor(ls, 32, 64);
      lrun[nf] += ls;
#pragma unroll
      for (int mf = 0; mf < 2; ++mf) {
        uint2 pk;
        pk.x = f2bf(p[mf][0]) | (f2bf(p[mf][1]) << 16);
        pk.y = f2bf(p[mf][2]) | (f2bf(p[mf][3]) << 16);
        *reinterpret_cast<uint2*>(&lP[wid][16 * nf + lrow][16 * mf + 4 * lhi]) = pk;
      }
    }

    // O^T += V . P^T
    bf16x8 pf0 = ld8(&lP[wid][lrow][8 * lhi]);
    bf16x8 pf1 = ld8(&lP[wid][16 + lrow][8 * lhi]);
    __builtin_amdgcn_s_setprio(1);
#pragma unroll
    for (int vs = 0; vs < 2; ++vs)
#pragma unroll
      for (int cf = 0; cf < 8; ++cf) {
        bf16x8 vf = ld8(&lV[g][vs][16 * cf + lrow][8 * lhi]);
        acc[0][vs][cf] = MFMA16(vf, pf0, acc[0][vs][cf]);
        acc[1][vs][cf] = MFMA16(vf, pf1, acc[1][vs][cf]);
      }
    __builtin_amdgcn_s_setprio(0);
    __syncthreads();
  }

  // ---- merge the 4 m-groups (2-level tree), then epilogue by group 0 ----
  auto wstate = [&](int s) {
    float* base = mb + (size_t)s * (132 * 64) + lane;
    base[0] = mrun[0]; base[64] = lrun[0]; base[128] = mrun[1]; base[192] = lrun[1];
#pragma unroll
    for (int nf = 0; nf < 2; ++nf)
#pragma unroll
      for (int vs = 0; vs < 2; ++vs)
#pragma unroll
        for (int cf = 0; cf < 8; ++cf)
#pragma unroll
          for (int r = 0; r < 4; ++r)
            base[(4 + ((nf * 2 + vs) * 8 + cf) * 4 + r) * 64] = acc[nf][vs][cf][r];
  };
  auto mstate = [&](int s) {
    float* base = mb + (size_t)s * (132 * 64) + lane;
    float a0[2], a1[2];
#pragma unroll
    for (int nf = 0; nf < 2; ++nf) {
      float m2 = base[(2 * nf) * 64], l2 = base[(2 * nf + 1) * 64];
      float M = fmaxf(mrun[nf], m2);
      a0[nf] = __builtin_amdgcn_exp2f((mrun[nf] - M) * L2E);
      a1[nf] = __builtin_amdgcn_exp2f((m2 - M) * L2E);
      lrun[nf] = lrun[nf] * a0[nf] + l2 * a1[nf];
      mrun[nf] = M;
    }
#pragma unroll
    for (int nf = 0; nf < 2; ++nf)
#pragma unroll
      for (int vs = 0; vs < 2; ++vs)
#pragma unroll
        for (int cf = 0; cf < 8; ++cf)
#pragma unroll
          for (int r = 0; r < 4; ++r)
            acc[nf][vs][cf][r] = acc[nf][vs][cf][r] * a0[nf] +
                                 base[(4 + ((nf * 2 + vs) * 8 + cf) * 4 + r) * 64] * a1[nf];
  };

  if (g == 1) wstate(j);
  if (g == 3) wstate(2 + j);
  __syncthreads();
  if (g == 0) mstate(j);
  if (g == 2) mstate(2 + j);
  __syncthreads();
  if (g == 2) wstate(j);
  __syncthreads();
  if (g == 0) {
    mstate(j);
    float inv[2] = {1.0f / lrun[0], 1.0f / lrun[1]};
#pragma unroll
    for (int nf = 0; nf < 2; ++nf) {
#pragma unroll
      for (int vs = 0; vs < 2; ++vs) {
#pragma unroll
        for (int cf = 0; cf < 8; ++cf) {
          int cb = 16 * cf + 4 * lhi;
          float4 cs = *reinterpret_cast<const float4*>(colsum + vs * 512 + b * 128 + cb);
          float y0 = cs.x - acc[nf][vs][cf][0] * inv[nf];
          float y1 = cs.y - acc[nf][vs][cf][1] * inv[nf];
          float y2 = cs.z - acc[nf][vs][cf][2] * inv[nf];
          float y3 = cs.w - acc[nf][vs][cf][3] * inv[nf];
          uint2 pk;
          pk.x = f2bf(y0) | (f2bf(y1) << 16);
          pk.y = f2bf(y2) | (f2bf(y3) << 16);
          *reinterpret_cast<uint2*>(Cat + ((size_t)(b * N_ + n0 + 32 * j + 16 * nf + lrow)) * OC_ +
                                    vs * 128 + cb) = pk;
        }
      }
    }
  }
}

// ---------- final projection: out[b][o][n] = relu((Wp . Cat^T)*s + sh), fp32 ----------
__global__ __launch_bounds__(256, 2) void dpf_fkern(const unsigned short* __restrict__ Cat,
                                                    const unsigned short* __restrict__ Wpb,
                                                    const float* __restrict__ bp,
                                                    const float* __restrict__ sp,
                                                    const float* __restrict__ tp,
                                                    float* __restrict__ out) {
  int bid = blockIdx.x;
  int b = bid >> 6, nt = bid & 63;
  int n0 = nt * 64;
  int t = threadIdx.x, lane = t & 63, wid = t >> 6;
  int lrow = lane & 15, lhi = lane >> 4;
  f32x4 acc[4][4];  // [nf][of]
#pragma unroll
  for (int i = 0; i < 4; ++i)
#pragma unroll
    for (int jj = 0; jj < 4; ++jj) acc[i][jj] = (f32x4){0.f, 0.f, 0.f, 0.f};
  const unsigned short* cbase = Cat + ((size_t)(b * N_ + n0 + lrow)) * OC_ + 8 * lhi;
  const unsigned short* wbase = Wpb + (size_t)(64 * wid + lrow) * OC_ + 8 * lhi;
  for (int ks = 0; ks < 8; ++ks) {
    bf16x8 af[4], bfv[4];
#pragma unroll
    for (int nf = 0; nf < 4; ++nf) af[nf] = ld8(cbase + (size_t)(16 * nf) * OC_ + 32 * ks);
#pragma unroll
    for (int of = 0; of < 4; ++of) bfv[of] = ld8(wbase + (size_t)(16 * of) * OC_ + 32 * ks);
#pragma unroll
    for (int nf = 0; nf < 4; ++nf)
#pragma unroll
      for (int of = 0; of < 4; ++of) acc[nf][of] = MFMA16(af[nf], bfv[of], acc[nf][of]);
  }
#pragma unroll
  for (int of = 0; of < 4; ++of) {
    int o = 64 * wid + 16 * of + lrow;
    float sc = sp[o];
    float sh = bp[o] * sc + tp[o];
#pragma unroll
    for (int nf = 0; nf < 4; ++nf) {
      float4 y;
      y.x = fmaxf(acc[nf][of][0] * sc + sh, 0.f);
      y.y = fmaxf(acc[nf][of][1] * sc + sh, 0.f);
      y.z = fmaxf(acc[nf][of][2] * sc + sh, 0.f);
      y.w = fmaxf(acc[nf][of][3] * sc + sh, 0.f);
      *reinterpret_cast<float4*>(out + ((size_t)(b * OC_ + o)) * N_ + n0 + 16 * nf + 4 * lhi) = y;
    }
  }
}

extern "C" void kernel_launch(void* const* d_in, const int* in_sizes, int n_in, void* d_out,
                              int out_size, void* d_ws, size_t ws_size, hipStream_t stream) {
  (void)in_sizes; (void)n_in; (void)out_size; (void)ws_size;
  const float* x1 = (const float*)d_in[0];
  const float* x2 = (const float*)d_in[1];
  const float* Wq = (const float*)d_in[2];
  const float* bq = (const float*)d_in[3];
  const float* sq = (const float*)d_in[4];
  const float* tq = (const float*)d_in[5];
  const float* Wk = (const float*)d_in[6];
  const float* bk = (const float*)d_in[7];
  const float* sk = (const float*)d_in[8];
  const float* tk = (const float*)d_in[9];
  const float* Wv = (const float*)d_in[10];
  const float* bv = (const float*)d_in[11];
  const float* sv = (const float*)d_in[12];
  const float* tv = (const float*)d_in[13];
  const float* Wp = (const float*)d_in[14];
  const float* bp = (const float*)d_in[15];
  const float* sp = (const float*)d_in[16];
  const float* tp = (const float*)d_in[17];

  char* w = (char*)d_ws;
  size_t o = 0;
  unsigned short* Xt = (unsigned short*)(w + o);  o += (size_t)2 * B_ * N_ * C_ * 2;   // 16,777,216
  unsigned short* Wqb = (unsigned short*)(w + o); o += (size_t)128 * 256 * 2;
  unsigned short* Wkb = (unsigned short*)(w + o); o += (size_t)128 * 256 * 2;
  unsigned short* Wvb = (unsigned short*)(w + o); o += (size_t)128 * 256 * 2;
  unsigned short* Wpb = (unsigned short*)(w + o); o += (size_t)256 * 256 * 2;
  unsigned short* Qg = (unsigned short*)(w + o);  o += (size_t)B_ * N_ * CI_ * 2;
  unsigned short* Kg = (unsigned short*)(w + o);  o += (size_t)B_ * N_ * CI_ * 2;
  unsigned short* V1g = (unsigned short*)(w + o); o += (size_t)B_ * N_ * CI_ * 2;
  unsigned short* V2g = (unsigned short*)(w + o); o += (size_t)B_ * N_ * CI_ * 2;
  unsigned short* Cat = (unsigned short*)(w + o); o += (size_t)B_ * N_ * OC_ * 2;
  float* csum = (float*)(w + o);                  o += (size_t)2 * B_ * CI_ * 4;       // ~42.3 MB total

  dpf_tkern<<<2048, 256, 0, stream>>>(x1, x2, Xt);
  dpf_wckern<<<80, 256, 0, stream>>>(Wq, Wk, Wv, Wp, Wqb, Wkb, Wvb, Wpb);
  dpf_pkern<<<512, 256, 0, stream>>>(Xt, Wqb, Wkb, Wvb, bq, sq, tq, bk, sk, tk, bv, sv, tv,
                                     Qg, Kg, V1g, V2g);
  dpf_cskern<<<1024, 256, 0, stream>>>(V1g, V2g, csum);
  dpf_akern<<<256, 512, 137216, stream>>>(Qg, Kg, V1g, V2g, csum, Cat);
  dpf_fkern<<<256, 256, 0, stream>>>(Cat, Wpb, bp, sp, tp, (float*)d_out);
}

// Round 4
// 237.249 us; speedup vs baseline: 1.6753x; 1.6753x over previous
//
#include <hip/hip_runtime.h>

#define B_ 4
#define C_ 256
#define CI_ 128
#define N_ 4096
#define OC_ 256

typedef __bf16 bf16x8 __attribute__((ext_vector_type(8)));
typedef float f32x4 __attribute__((ext_vector_type(4)));

#define MFMA16(a, b, c) __builtin_amdgcn_mfma_f32_16x16x32_bf16((a), (b), (c), 0, 0, 0)

__device__ __forceinline__ unsigned f2bf(float f) {
  unsigned u = __float_as_uint(f);
  return (u + 0x7fffu + ((u >> 16) & 1u)) >> 16;
}
__device__ __forceinline__ float b2f(unsigned h) { return __uint_as_float(h << 16); }
__device__ __forceinline__ bf16x8 ld8(const unsigned short* p) {
  return *reinterpret_cast<const bf16x8*>(p);
}
// async global->LDS, 16B per lane, wave-uniform LDS dest + lane*16
__device__ __forceinline__ void gll16(const void* g, void* l) {
  __builtin_amdgcn_global_load_lds((const __attribute__((address_space(1))) void*)g,
                                   (__attribute__((address_space(3))) void*)l, 16, 0, 0);
}

// ---------- transpose+convert: x f32 [B][256][4096] -> Xt bf16 [B][4096][256] ----------
__global__ __launch_bounds__(256) void dpf_tkern(const float* __restrict__ x1,
                                                 const float* __restrict__ x2,
                                                 unsigned short* __restrict__ xt) {
  __shared__ float lt[64][65];
  int bid = blockIdx.x;
  int src = bid >> 10, rem = bid & 1023;
  int b = rem >> 8, ct = (rem >> 6) & 3, nt = rem & 63;
  const float* x = src ? x2 : x1;
  unsigned short* dst = xt + (size_t)src * ((size_t)B_ * N_ * C_);
  int t = threadIdx.x;
  int cl = t >> 2, nlo = (t & 3) << 4;
  const float* rp = x + ((size_t)(b * C_ + ct * 64 + cl)) * N_ + nt * 64 + nlo;
#pragma unroll
  for (int q = 0; q < 4; ++q) {
    float4 v = *reinterpret_cast<const float4*>(rp + q * 4);
    lt[cl][nlo + q * 4 + 0] = v.x;
    lt[cl][nlo + q * 4 + 1] = v.y;
    lt[cl][nlo + q * 4 + 2] = v.z;
    lt[cl][nlo + q * 4 + 3] = v.w;
  }
  __syncthreads();
  int nl = t & 63, cb = (t >> 6) << 4;
  unsigned h[16];
#pragma unroll
  for (int q = 0; q < 16; ++q) h[q] = f2bf(lt[cb + q][nl]);
  uint4 u0, u1;
  u0.x = h[0] | (h[1] << 16); u0.y = h[2] | (h[3] << 16);
  u0.z = h[4] | (h[5] << 16); u0.w = h[6] | (h[7] << 16);
  u1.x = h[8] | (h[9] << 16); u1.y = h[10] | (h[11] << 16);
  u1.z = h[12] | (h[13] << 16); u1.w = h[14] | (h[15] << 16);
  unsigned short* op = dst + ((size_t)(b * N_ + nt * 64 + nl)) * C_ + ct * 64 + cb;
  *reinterpret_cast<uint4*>(op) = u0;
  *reinterpret_cast<uint4*>(op + 8) = u1;
}

// ---------- weight convert to bf16 ----------
__global__ __launch_bounds__(256) void dpf_wckern(
    const float* __restrict__ Wq, const float* __restrict__ Wk, const float* __restrict__ Wv,
    const float* __restrict__ Wp, unsigned short* __restrict__ Wqb, unsigned short* __restrict__ Wkb,
    unsigned short* __restrict__ Wvb, unsigned short* __restrict__ Wpb) {
  int bid = blockIdx.x;
  const float* src;
  unsigned short* dst;
  int lb;
  if (bid < 16) { src = Wq; dst = Wqb; lb = bid; }
  else if (bid < 32) { src = Wk; dst = Wkb; lb = bid - 16; }
  else if (bid < 48) { src = Wv; dst = Wvb; lb = bid - 32; }
  else { src = Wp; dst = Wpb; lb = bid - 48; }
  int o = lb * 2048 + threadIdx.x * 8;
  float4 a = *reinterpret_cast<const float4*>(src + o);
  float4 c = *reinterpret_cast<const float4*>(src + o + 4);
  uint4 u;
  u.x = f2bf(a.x) | (f2bf(a.y) << 16);
  u.y = f2bf(a.z) | (f2bf(a.w) << 16);
  u.z = f2bf(c.x) | (f2bf(c.y) << 16);
  u.w = f2bf(c.z) | (f2bf(c.w) << 16);
  *reinterpret_cast<uint4*>(dst + o) = u;
}

// ---------- projections ----------
// Q -> Qg [b][n][128] plain
// K -> Kt [b][n][128 c, granule-XOR-swizzled by n&7]   (LDS tile image for gll)
// V -> Vt [b][step=n>>7][vs][128 c][128 m, granule-XOR-swizzled by c&7]; vs0=V2, vs1=V1
__global__ __launch_bounds__(256, 2) void dpf_pkern(
    const unsigned short* __restrict__ Xt, const unsigned short* __restrict__ Wqb,
    const unsigned short* __restrict__ Wkb, const unsigned short* __restrict__ Wvb,
    const float* __restrict__ bq, const float* __restrict__ sq, const float* __restrict__ tq,
    const float* __restrict__ bk, const float* __restrict__ sk, const float* __restrict__ tk,
    const float* __restrict__ bv, const float* __restrict__ sv, const float* __restrict__ tv,
    unsigned short* __restrict__ Qg, unsigned short* __restrict__ Kt,
    unsigned short* __restrict__ Vt) {
  int bid = blockIdx.x;
  int g = bid >> 7, b = (bid >> 5) & 3, nt = bid & 31;
  int n0 = nt * 128;
  int t = threadIdx.x, lane = t & 63, wid = t >> 6;
  int wo = wid >> 1, wn = wid & 1;
  int lrow = lane & 15, lhi = lane >> 4;

  const unsigned short* W = (g == 0) ? Wqb : (g == 1) ? Wkb : Wvb;
  const unsigned short* X = Xt + ((g == 0 || g == 2) ? (size_t)0 : (size_t)B_ * N_ * C_);
  const float* bb = (g == 0) ? bq : (g == 1) ? bk : bv;
  const float* ss = (g == 0) ? sq : (g == 1) ? sk : sv;
  const float* tt = (g == 0) ? tq : (g == 1) ? tk : tv;
  const float extra = (g < 2) ? 0.29730177875068026f : 1.0f;  // 128^-0.25 folded into Q and K

  f32x4 acc[4][4];
#pragma unroll
  for (int i = 0; i < 4; ++i)
#pragma unroll
    for (int jj = 0; jj < 4; ++jj) acc[i][jj] = (f32x4){0.f, 0.f, 0.f, 0.f};

  const unsigned short* wbase = W + (size_t)(64 * wo + lrow) * C_ + 8 * lhi;
  const unsigned short* xbase = X + ((size_t)(b * N_ + n0 + 64 * wn + lrow)) * C_ + 8 * lhi;

  for (int ks = 0; ks < 8; ++ks) {
    bf16x8 wf[4], xf[4];
#pragma unroll
    for (int of = 0; of < 4; ++of) wf[of] = ld8(wbase + (size_t)(16 * of) * C_ + 32 * ks);
#pragma unroll
    for (int nf = 0; nf < 4; ++nf) xf[nf] = ld8(xbase + (size_t)(16 * nf) * C_ + 32 * ks);
    if (g < 2) {
#pragma unroll
      for (int of = 0; of < 4; ++of)
#pragma unroll
        for (int nf = 0; nf < 4; ++nf) acc[of][nf] = MFMA16(wf[of], xf[nf], acc[of][nf]);
    } else {
#pragma unroll
      for (int of = 0; of < 4; ++of)
#pragma unroll
        for (int nf = 0; nf < 4; ++nf) acc[of][nf] = MFMA16(xf[nf], wf[of], acc[of][nf]);
    }
  }

  if (g < 2) {
    // D: row = o (4*lhi+r), col = n (lrow)
#pragma unroll
    for (int of = 0; of < 4; ++of) {
      int ob = 64 * wo + 16 * of + 4 * lhi;
      float4 s4 = *reinterpret_cast<const float4*>(ss + ob);
      float4 b4 = *reinterpret_cast<const float4*>(bb + ob);
      float4 t4 = *reinterpret_cast<const float4*>(tt + ob);
      float sc0 = s4.x * extra, sc1 = s4.y * extra, sc2 = s4.z * extra, sc3 = s4.w * extra;
      float sh0 = (b4.x * s4.x + t4.x) * extra, sh1 = (b4.y * s4.y + t4.y) * extra;
      float sh2 = (b4.z * s4.z + t4.z) * extra, sh3 = (b4.w * s4.w + t4.w) * extra;
#pragma unroll
      for (int nf = 0; nf < 4; ++nf) {
        int n = n0 + 64 * wn + 16 * nf + lrow;
        float y0 = fmaxf(acc[of][nf][0] * sc0 + sh0, 0.f);
        float y1 = fmaxf(acc[of][nf][1] * sc1 + sh1, 0.f);
        float y2 = fmaxf(acc[of][nf][2] * sc2 + sh2, 0.f);
        float y3 = fmaxf(acc[of][nf][3] * sc3 + sh3, 0.f);
        uint2 pk;
        pk.x = f2bf(y0) | (f2bf(y1) << 16);
        pk.y = f2bf(y2) | (f2bf(y3) << 16);
        if (g == 0) {
          *reinterpret_cast<uint2*>(Qg + ((size_t)(b * N_ + n)) * CI_ + ob) = pk;
        } else {
          // K tile image: [b][n][c ^ ((n&7)<<3)]
          size_t idx = (size_t)b * 524288 + (size_t)n * 128 + (ob ^ ((n & 7) << 3));
          *reinterpret_cast<uint2*>(Kt + idx) = pk;
        }
      }
    }
  } else {
    // D: row = n (4*lhi+r), col = o (lrow)
    int vs = (g == 2) ? 1 : 0;  // vs0 = V2 (out1), vs1 = V1 (out2)
#pragma unroll
    for (int of = 0; of < 4; ++of) {
      int o = 64 * wo + 16 * of + lrow;
      float sc = ss[o];
      float sh = bb[o] * sc + tt[o];
#pragma unroll
      for (int nf = 0; nf < 4; ++nf) {
        int nb = n0 + 64 * wn + 16 * nf + 4 * lhi;
        float y0 = fmaxf(acc[of][nf][0] * sc + sh, 0.f);
        float y1 = fmaxf(acc[of][nf][1] * sc + sh, 0.f);
        float y2 = fmaxf(acc[of][nf][2] * sc + sh, 0.f);
        float y3 = fmaxf(acc[of][nf][3] * sc + sh, 0.f);
        uint2 pk;
        pk.x = f2bf(y0) | (f2bf(y1) << 16);
        pk.y = f2bf(y2) | (f2bf(y3) << 16);
        // V tile image: [b][nb>>7][vs][o][ (nb&127) ^ ((o&7)<<3) ]
        size_t idx = (size_t)b * 1048576 + (size_t)(nb >> 7) * 32768 + (size_t)vs * 16384 +
                     (size_t)o * 128 + ((nb & 127) ^ ((o & 7) << 3));
        *reinterpret_cast<uint2*>(Vt + idx) = pk;
      }
    }
  }
}

// ---------- column sums of V over n (tiled Vt layout; XOR perm is sum-invariant) ----------
__global__ __launch_bounds__(256) void dpf_cskern(const unsigned short* __restrict__ Vt,
                                                  float* __restrict__ colsum) {
  __shared__ float ps[4];
  int bid = blockIdx.x;
  int vs = bid >> 9, b = (bid >> 7) & 3, c = bid & 127;
  int t = threadIdx.x;
  const unsigned short* src = Vt + (size_t)b * 1048576 + (size_t)(t >> 3) * 32768 +
                              (size_t)vs * 16384 + (size_t)c * 128 + (t & 7) * 16;
  float s = 0.f;
#pragma unroll
  for (int i = 0; i < 2; ++i) {
    uint4 u = *reinterpret_cast<const uint4*>(src + i * 8);
    s += b2f(u.x & 0xffffu) + b2f(u.x >> 16) + b2f(u.y & 0xffffu) + b2f(u.y >> 16);
    s += b2f(u.z & 0xffffu) + b2f(u.z >> 16) + b2f(u.w & 0xffffu) + b2f(u.w >> 16);
  }
#pragma unroll
  for (int off = 1; off < 64; off <<= 1) s += __shfl_xor(s, off, 64);
  if ((t & 63) == 0) ps[t >> 6] = s;
  __syncthreads();
  if (t == 0) colsum[vs * 512 + b * 128 + c] = ps[0] + ps[1] + ps[2] + ps[3];
}

// ---------- fused complement flash-attention ----------
// grid 256, 512 threads = 8 waves = 4 m-groups(g) x 2 q-waves(j) x 32 q-rows, m-tile 128/step
// K: double-buffered 2x32KB via global_load_lds; V: single 64KB via global_load_lds
// (arch-VGPR demand ~110 < 128 cap; r1-r3: reg staging spilled 46 regs -> 783MB scratch)
__global__ __launch_bounds__(512)
__attribute__((amdgpu_waves_per_eu(2, 2))) void dpf_akern(
    const unsigned short* __restrict__ Qg, const unsigned short* __restrict__ Kt,
    const unsigned short* __restrict__ Vt, const float* __restrict__ colsum,
    unsigned short* __restrict__ Cat) {
  extern __shared__ char smem[];
  // [0,64K): K dbuf [2][128][128];  [64K,128K): V [2 vs][128 c][128 m];  [128K,148K): lP
  unsigned short(*lP)[32][40] = reinterpret_cast<unsigned short(*)[32][40]>(smem + 131072);
  float* mb = reinterpret_cast<float*>(smem);  // merge overlay (after main loop)

  const float L2E = 1.44269504088896f;
  int t = threadIdx.x, lane = t & 63, wid = t >> 6;
  int g = wid >> 1, j = wid & 1;
  int lrow = lane & 15, lhi = lane >> 4;
  int swz = (lrow & 7) << 3;

  int bid = blockIdx.x;
  int xcd = bid & 7;
  int b = xcd >> 1;  // each XCD pair owns one batch (L2 locality)
  int qt = ((bid >> 3) << 1) | (xcd & 1);
  int n0 = qt * 64;

  // Q fragments (B-operand of S^T): lane owns one q-row per nf
  bf16x8 qf[2][4];
#pragma unroll
  for (int nf = 0; nf < 2; ++nf) {
    const unsigned short* qp = Qg + ((size_t)(b * N_ + n0 + 32 * j + 16 * nf + lrow)) * CI_ + 8 * lhi;
#pragma unroll
    for (int ks = 0; ks < 4; ++ks) qf[nf][ks] = ld8(qp + 32 * ks);
  }

  f32x4 acc[2][2][8];  // [nf][vs][cf]; O^T frags (AGPR side)
#pragma unroll
  for (int nf = 0; nf < 2; ++nf)
#pragma unroll
    for (int vs = 0; vs < 2; ++vs)
#pragma unroll
      for (int cf = 0; cf < 8; ++cf) acc[nf][vs][cf] = (f32x4){0.f, 0.f, 0.f, 0.f};
  float mrun[2] = {-1e30f, -1e30f}, lrun[2] = {0.f, 0.f};

  // gll source bases (byte addresses; global layouts are LDS tile images)
  const char* kb = (const char*)Kt + (size_t)b * 1048576 + wid * 4096 + lane * 16;
  const char* vb = (const char*)Vt + (size_t)b * 2097152 + wid * 8192 + lane * 16;

  // prologue: K(0) -> buf0
#pragma unroll
  for (int e = 0; e < 4; ++e) gll16(kb + e * 1024, smem + (wid * 4 + e) * 1024);
  __syncthreads();  // includes vmcnt(0)

  int cur = 0;
#pragma unroll 1
  for (int step = 0; step < 32; ++step) {
    // issue V(step) (8 x 1KB per wave), then K(step+1) -> K[cur^1] (4 x 1KB)
    const char* vsrc = vb + (size_t)step * 65536;
#pragma unroll
    for (int e = 0; e < 8; ++e) gll16(vsrc + e * 1024, smem + 65536 + (wid * 8 + e) * 1024);
    const char* ksrc = kb + (size_t)((step + 1) & 31) * 32768;
#pragma unroll
    for (int e = 0; e < 4; ++e)
      gll16(ksrc + e * 1024, smem + (cur ^ 1) * 32768 + (wid * 4 + e) * 1024);

    // S^T = K . Q^T from K[cur] (resident since end of previous iter)
    const unsigned short* lk = (const unsigned short*)(smem + cur * 32768);
    f32x4 sacc[2][2];
#pragma unroll
    for (int nf = 0; nf < 2; ++nf)
#pragma unroll
      for (int mf = 0; mf < 2; ++mf) sacc[nf][mf] = (f32x4){0.f, 0.f, 0.f, 0.f};
    __builtin_amdgcn_s_setprio(1);
#pragma unroll
    for (int ks = 0; ks < 4; ++ks) {
      int ci = (32 * ks + 8 * lhi) ^ swz;
      bf16x8 kf0 = ld8(lk + (32 * g + lrow) * 128 + ci);
      bf16x8 kf1 = ld8(lk + (32 * g + 16 + lrow) * 128 + ci);
#pragma unroll
      for (int nf = 0; nf < 2; ++nf) {
        sacc[nf][0] = MFMA16(kf0, qf[nf][ks], sacc[nf][0]);
        sacc[nf][1] = MFMA16(kf1, qf[nf][ks], sacc[nf][1]);
      }
    }
    __builtin_amdgcn_s_setprio(0);

    // online softmax per q-row (one row per lane per nf), P -> LDS (wave-local)
#pragma unroll
    for (int nf = 0; nf < 2; ++nf) {
      float smax = fmaxf(fmaxf(fmaxf(sacc[nf][0][0], sacc[nf][0][1]), fmaxf(sacc[nf][0][2], sacc[nf][0][3])),
                         fmaxf(fmaxf(sacc[nf][1][0], sacc[nf][1][1]), fmaxf(sacc[nf][1][2], sacc[nf][1][3])));
      smax = fmaxf(smax, __shfl_xor(smax, 16, 64));
      smax = fmaxf(smax, __shfl_xor(smax, 32, 64));
      // T13 defer-rescale: skip the acc pass while max growth <= 8 (wave-uniform)
      if (!__all(smax - mrun[nf] <= 8.0f)) {
        float mnew = fmaxf(mrun[nf], smax);
        float fsc = __builtin_amdgcn_exp2f((mrun[nf] - mnew) * L2E);
        mrun[nf] = mnew;
        lrun[nf] *= fsc;
#pragma unroll
        for (int vs = 0; vs < 2; ++vs)
#pragma unroll
          for (int cf = 0; cf < 8; ++cf) acc[nf][vs][cf] *= fsc;
      }
      float p[2][4];
      float ls = 0.f;
#pragma unroll
      for (int mf = 0; mf < 2; ++mf)
#pragma unroll
        for (int r = 0; r < 4; ++r) {
          p[mf][r] = __builtin_amdgcn_exp2f((sacc[nf][mf][r] - mrun[nf]) * L2E);
          ls += p[mf][r];
        }
      ls += __shfl_xor(ls, 16, 64);
      ls += __shfl_xor(ls, 32, 64);
      lrun[nf] += ls;
#pragma unroll
      for (int mf = 0; mf < 2; ++mf) {
        uint2 pk;
        pk.x = f2bf(p[mf][0]) | (f2bf(p[mf][1]) << 16);
        pk.y = f2bf(p[mf][2]) | (f2bf(p[mf][3]) << 16);
        *reinterpret_cast<uint2*>(&lP[wid][16 * nf + lrow][16 * mf + 4 * lhi]) = pk;
      }
    }

    // wait V resident (counted: K(step+1)'s 4 loads keep flying), then barrier
    asm volatile("s_waitcnt vmcnt(4)\ns_barrier" ::: "memory");

    // O^T += V . P^T
    const unsigned short* lv = (const unsigned short*)(smem + 65536);
    bf16x8 pf0 = ld8(&lP[wid][lrow][8 * lhi]);
    bf16x8 pf1 = ld8(&lP[wid][16 + lrow][8 * lhi]);
    int mi = (32 * g + 8 * lhi) ^ swz;
    __builtin_amdgcn_s_setprio(1);
#pragma unroll
    for (int vs = 0; vs < 2; ++vs)
#pragma unroll
      for (int cf = 0; cf < 8; ++cf) {
        bf16x8 vf = ld8(lv + (vs * 128 + 16 * cf + lrow) * 128 + mi);
        acc[0][vs][cf] = MFMA16(vf, pf0, acc[0][vs][cf]);
        acc[1][vs][cf] = MFMA16(vf, pf1, acc[1][vs][cf]);
      }
    __builtin_amdgcn_s_setprio(0);
    __syncthreads();  // drains vmcnt(0): K(step+1) resident for next iter
    cur ^= 1;
  }
  __syncthreads();  // safety before LDS overlay reuse

  // ---- merge the 4 m-groups (2-level tree), then epilogue by group 0 ----
  auto wstate = [&](int s) {
    float* base = mb + (size_t)s * (132 * 64) + lane;
    base[0] = mrun[0]; base[64] = lrun[0]; base[128] = mrun[1]; base[192] = lrun[1];
#pragma unroll
    for (int nf = 0; nf < 2; ++nf)
#pragma unroll
      for (int vs = 0; vs < 2; ++vs)
#pragma unroll
        for (int cf = 0; cf < 8; ++cf)
#pragma unroll
          for (int r = 0; r < 4; ++r)
            base[(4 + ((nf * 2 + vs) * 8 + cf) * 4 + r) * 64] = acc[nf][vs][cf][r];
  };
  auto mstate = [&](int s) {
    float* base = mb + (size_t)s * (132 * 64) + lane;
    float a0[2], a1[2];
#pragma unroll
    for (int nf = 0; nf < 2; ++nf) {
      float m2 = base[(2 * nf) * 64], l2 = base[(2 * nf + 1) * 64];
      float M = fmaxf(mrun[nf], m2);
      a0[nf] = __builtin_amdgcn_exp2f((mrun[nf] - M) * L2E);
      a1[nf] = __builtin_amdgcn_exp2f((m2 - M) * L2E);
      lrun[nf] = lrun[nf] * a0[nf] + l2 * a1[nf];
      mrun[nf] = M;
    }
#pragma unroll
    for (int nf = 0; nf < 2; ++nf)
#pragma unroll
      for (int vs = 0; vs < 2; ++vs)
#pragma unroll
        for (int cf = 0; cf < 8; ++cf)
#pragma unroll
          for (int r = 0; r < 4; ++r)
            acc[nf][vs][cf][r] = acc[nf][vs][cf][r] * a0[nf] +
                                 base[(4 + ((nf * 2 + vs) * 8 + cf) * 4 + r) * 64] * a1[nf];
  };

  if (g == 1) wstate(j);
  if (g == 3) wstate(2 + j);
  __syncthreads();
  if (g == 0) mstate(j);
  if (g == 2) mstate(2 + j);
  __syncthreads();
  if (g == 2) wstate(j);
  __syncthreads();
  if (g == 0) {
    mstate(j);
    float inv[2] = {1.0f / lrun[0], 1.0f / lrun[1]};
#pragma unroll
    for (int nf = 0; nf < 2; ++nf) {
#pragma unroll
      for (int vs = 0; vs < 2; ++vs) {
#pragma unroll
        for (int cf = 0; cf < 8; ++cf) {
          int cb = 16 * cf + 4 * lhi;
          float4 cs = *reinterpret_cast<const float4*>(colsum + vs * 512 + b * 128 + cb);
          float y0 = cs.x - acc[nf][vs][cf][0] * inv[nf];
          float y1 = cs.y - acc[nf][vs][cf][1] * inv[nf];
          float y2 = cs.z - acc[nf][vs][cf][2] * inv[nf];
          float y3 = cs.w - acc[nf][vs][cf][3] * inv[nf];
          uint2 pk;
          pk.x = f2bf(y0) | (f2bf(y1) << 16);
          pk.y = f2bf(y2) | (f2bf(y3) << 16);
          *reinterpret_cast<uint2*>(Cat + ((size_t)(b * N_ + n0 + 32 * j + 16 * nf + lrow)) * OC_ +
                                    vs * 128 + cb) = pk;
        }
      }
    }
  }
}

// ---------- final projection: out[b][o][n] = relu((Wp . Cat^T)*s + sh), fp32 ----------
__global__ __launch_bounds__(256, 2) void dpf_fkern(const unsigned short* __restrict__ Cat,
                                                    const unsigned short* __restrict__ Wpb,
                                                    const float* __restrict__ bp,
                                                    const float* __restrict__ sp,
                                                    const float* __restrict__ tp,
                                                    float* __restrict__ out) {
  int bid = blockIdx.x;
  int b = bid >> 6, nt = bid & 63;
  int n0 = nt * 64;
  int t = threadIdx.x, lane = t & 63, wid = t >> 6;
  int lrow = lane & 15, lhi = lane >> 4;
  f32x4 acc[4][4];  // [nf][of]
#pragma unroll
  for (int i = 0; i < 4; ++i)
#pragma unroll
    for (int jj = 0; jj < 4; ++jj) acc[i][jj] = (f32x4){0.f, 0.f, 0.f, 0.f};
  const unsigned short* cbase = Cat + ((size_t)(b * N_ + n0 + lrow)) * OC_ + 8 * lhi;
  const unsigned short* wbase = Wpb + (size_t)(64 * wid + lrow) * OC_ + 8 * lhi;
  for (int ks = 0; ks < 8; ++ks) {
    bf16x8 af[4], bfv[4];
#pragma unroll
    for (int nf = 0; nf < 4; ++nf) af[nf] = ld8(cbase + (size_t)(16 * nf) * OC_ + 32 * ks);
#pragma unroll
    for (int of = 0; of < 4; ++of) bfv[of] = ld8(wbase + (size_t)(16 * of) * OC_ + 32 * ks);
#pragma unroll
    for (int nf = 0; nf < 4; ++nf)
#pragma unroll
      for (int of = 0; of < 4; ++of) acc[nf][of] = MFMA16(af[nf], bfv[of], acc[nf][of]);
  }
#pragma unroll
  for (int of = 0; of < 4; ++of) {
    int o = 64 * wid + 16 * of + lrow;
    float sc = sp[o];
    float sh = bp[o] * sc + tp[o];
#pragma unroll
    for (int nf = 0; nf < 4; ++nf) {
      float4 y;
      y.x = fmaxf(acc[nf][of][0] * sc + sh, 0.f);
      y.y = fmaxf(acc[nf][of][1] * sc + sh, 0.f);
      y.z = fmaxf(acc[nf][of][2] * sc + sh, 0.f);
      y.w = fmaxf(acc[nf][of][3] * sc + sh, 0.f);
      *reinterpret_cast<float4*>(out + ((size_t)(b * OC_ + o)) * N_ + n0 + 16 * nf + 4 * lhi) = y;
    }
  }
}

extern "C" void kernel_launch(void* const* d_in, const int* in_sizes, int n_in, void* d_out,
                              int out_size, void* d_ws, size_t ws_size, hipStream_t stream) {
  (void)in_sizes; (void)n_in; (void)out_size; (void)ws_size;
  const float* x1 = (const float*)d_in[0];
  const float* x2 = (const float*)d_in[1];
  const float* Wq = (const float*)d_in[2];
  const float* bq = (const float*)d_in[3];
  const float* sq = (const float*)d_in[4];
  const float* tq = (const float*)d_in[5];
  const float* Wk = (const float*)d_in[6];
  const float* bk = (const float*)d_in[7];
  const float* sk = (const float*)d_in[8];
  const float* tk = (const float*)d_in[9];
  const float* Wv = (const float*)d_in[10];
  const float* bv = (const float*)d_in[11];
  const float* sv = (const float*)d_in[12];
  const float* tv = (const float*)d_in[13];
  const float* Wp = (const float*)d_in[14];
  const float* bp = (const float*)d_in[15];
  const float* sp = (const float*)d_in[16];
  const float* tp = (const float*)d_in[17];

  char* w = (char*)d_ws;
  size_t o = 0;
  unsigned short* Xt = (unsigned short*)(w + o);  o += (size_t)2 * B_ * N_ * C_ * 2;   // 16 MB
  unsigned short* Wqb = (unsigned short*)(w + o); o += (size_t)128 * 256 * 2;
  unsigned short* Wkb = (unsigned short*)(w + o); o += (size_t)128 * 256 * 2;
  unsigned short* Wvb = (unsigned short*)(w + o); o += (size_t)128 * 256 * 2;
  unsigned short* Wpb = (unsigned short*)(w + o); o += (size_t)256 * 256 * 2;
  unsigned short* Qg = (unsigned short*)(w + o);  o += (size_t)B_ * N_ * CI_ * 2;      // 4 MB
  unsigned short* Kt = (unsigned short*)(w + o);  o += (size_t)B_ * N_ * CI_ * 2;      // 4 MB
  unsigned short* Vt = (unsigned short*)(w + o);  o += (size_t)2 * B_ * N_ * CI_ * 2;  // 8 MB
  unsigned short* Cat = (unsigned short*)(w + o); o += (size_t)B_ * N_ * OC_ * 2;      // 8 MB
  float* csum = (float*)(w + o);                  o += (size_t)2 * B_ * CI_ * 4;

  dpf_tkern<<<2048, 256, 0, stream>>>(x1, x2, Xt);
  dpf_wckern<<<80, 256, 0, stream>>>(Wq, Wk, Wv, Wp, Wqb, Wkb, Wvb, Wpb);
  dpf_pkern<<<512, 256, 0, stream>>>(Xt, Wqb, Wkb, Wvb, bq, sq, tq, bk, sk, tk, bv, sv, tv,
                                     Qg, Kt, Vt);
  dpf_cskern<<<1024, 256, 0, stream>>>(Vt, csum);
  dpf_akern<<<256, 512, 151552, stream>>>(Qg, Kt, Vt, csum, Cat);
  dpf_fkern<<<256, 256, 0, stream>>>(Cat, Wpb, bp, sp, tp, (float*)d_out);
}